// Round 6
// baseline (127.025 us; speedup 1.0000x reference)
//
#include <hip/hip_runtime.h>
#include <hip/hip_bf16.h>

// Single fused kernel, grid = 160 blocks x 256 threads.
// Every block redundantly runs the tiny encoder (proven R3 stage code) from
// an LDS-staged weight arena kept in the INPUT dtype; block o computes
// decoder output o from its own LDS latent with a register-prefetched
// weight row. Input dtype (f32 vs bf16) sniffed from ln1_g (all-ones):
// 0x3F803F80 => bf16 pair, 0x3F800000 => f32. Evidence (R1..R5): the
// sniff kernels passed, hard-coded-bf16 kernels NaN'd => inputs are f32;
// keep both paths (sniff is one uniform scalar load).

#define NW 3
#define NHOST 16
#define DM 16
#define FFD 64
#define LAT 768

typedef __hip_bfloat16 bf16;
typedef __attribute__((ext_vector_type(8))) unsigned short ushort8v;

static __device__ __forceinline__ float u2f(unsigned short u) {
    return __uint_as_float(((unsigned)u) << 16);
}

// arena accessor (arena stored in input dtype)
static __device__ __forceinline__ float lwf(const unsigned short* a, int i) { return u2f(a[i]); }
static __device__ __forceinline__ float lwf(const float* a, int i) { return a[i]; }

// global scalar load / store
static __device__ __forceinline__ float gld(const bf16* p, int i) { return __bfloat162float(p[i]); }
static __device__ __forceinline__ float gld(const float* p, int i) { return p[i]; }
static __device__ __forceinline__ void gst(bf16* p, int i, float v) { p[i] = __float2bfloat16(v); }
static __device__ __forceinline__ void gst(float* p, int i, float v) { p[i] = v; }

// ---- LDS weight-arena element offsets (all multiples of 8) ----
enum {
    OFF_T    = 0,     // 144
    OFF_GATW = 144,   // 48
    OFF_ASRC = 192,   // 16
    OFF_ADST = 208,   // 16
    OFF_TEW  = 224,   // 256
    OFF_TEB  = 480,   // 16
    OFF_PE   = 496,   // 48
    OFF_QKVW = 544,   // 1536
    OFF_QKVB = 2080,  // 96
    OFF_OUTW = 2176,  // 512
    OFF_OUTB = 2688,  // 32
    OFF_LN1G = 2720,  // 32
    OFF_LN1B = 2752,  // 32
    OFF_FF1W = 2784,  // 2048
    OFF_FF1B = 4832,  // 128
    OFF_FF2W = 4960,  // 2048
    OFF_FF2B = 7008,  // 32
    OFF_LN2G = 7040,  // 32
    OFF_LN2B = 7072,  // 32
    TOTAL_W  = 7104
};

struct Smem {
    float h[NW][NHOST][DM];
    float esrc[NW][NHOST];
    float edst[NW][NHOST];
    float alpha[NW][NHOST][NHOST];  // [w][src][dst]
    float xe[NW][NHOST][DM];
    float qkv[NW][NHOST][48];
    float ctx[NW][NHOST][DM];
    float tmp[NW][NHOST][DM];
    float ffh[NW][NHOST][FFD];
    float latent[LAT];
    float part[4];
};

template<typename T, typename WT>
__device__ void run_all(Smem& sm, WT* smW, int tid, int o,
    const T* t, const T* gat_W, const T* a_src, const T* a_dst,
    const T* te_W, const T* te_b, const T* pe,
    const T* qkv_W, const T* qkv_b, const T* out_W, const T* out_b,
    const T* ln1_g, const T* ln1_b,
    const T* ff1_W, const T* ff1_b, const T* ff2_W, const T* ff2_b,
    const T* ln2_g, const T* ln2_b,
    const T* an_W, const T* an_b, const T* pr_W, const T* pr_b,
    T* out)
{
    // ---- prefetch this block's decoder weight slice (hidden behind encode)
    T wr0{}, wr1{}, wr2{}, wr3{};
    if (tid < 192) {
        const T* Wr = (o < 32) ? (an_W + o * LAT) : (pr_W + (o - 32) * LAT);
        wr0 = Wr[tid * 4];     wr1 = Wr[tid * 4 + 1];
        wr2 = Wr[tid * 4 + 2]; wr3 = Wr[tid * 4 + 3];
    }

    // ---- stage all encoder weights + input into LDS (proven R2-sub loop) ----
    {
        constexpr int EPC = 16 / (int)sizeof(T);       // elems per 16B chunk
        constexpr int NCHUNK = TOTAL_W / EPC;
        for (int g = tid; g < NCHUNK; g += 256) {
            int e = g * EPC;
            const T* p; int base;
            if      (e < OFF_GATW) { p = t;      base = OFF_T; }
            else if (e < OFF_ASRC) { p = gat_W;  base = OFF_GATW; }
            else if (e < OFF_ADST) { p = a_src;  base = OFF_ASRC; }
            else if (e < OFF_TEW)  { p = a_dst;  base = OFF_ADST; }
            else if (e < OFF_TEB)  { p = te_W;   base = OFF_TEW; }
            else if (e < OFF_PE)   { p = te_b;   base = OFF_TEB; }
            else if (e < OFF_QKVW) { p = pe;     base = OFF_PE; }
            else if (e < OFF_QKVB) { p = qkv_W;  base = OFF_QKVW; }
            else if (e < OFF_OUTW) { p = qkv_b;  base = OFF_QKVB; }
            else if (e < OFF_OUTB) { p = out_W;  base = OFF_OUTW; }
            else if (e < OFF_LN1G) { p = out_b;  base = OFF_OUTB; }
            else if (e < OFF_LN1B) { p = ln1_g;  base = OFF_LN1G; }
            else if (e < OFF_FF1W) { p = ln1_b;  base = OFF_LN1B; }
            else if (e < OFF_FF1B) { p = ff1_W;  base = OFF_FF1W; }
            else if (e < OFF_FF2W) { p = ff1_b;  base = OFF_FF1B; }
            else if (e < OFF_FF2B) { p = ff2_W;  base = OFF_FF2W; }
            else if (e < OFF_LN2G) { p = ff2_b;  base = OFF_FF2B; }
            else if (e < OFF_LN2B) { p = ln2_g;  base = OFF_LN2G; }
            else                   { p = ln2_b;  base = OFF_LN2B; }
            *(ushort8v*)((unsigned char*)smW + (size_t)e * sizeof(T)) =
                *(const ushort8v*)(p + (e - base));
        }
    }
    __syncthreads();

    // ---- GAT: h[w][n][f] = sum_i x[w,n,i] * gat_W[i,f] ----
    for (int idx = tid; idx < NW * NHOST * DM; idx += 256) {
        int w = idx >> 8, r = idx & 255, n = r >> 4, f = r & 15;
        float acc = 0.f;
        #pragma unroll
        for (int i = 0; i < 3; ++i)
            acc += lwf(smW, OFF_T + (w * NHOST + n) * 3 + i) * lwf(smW, OFF_GATW + i * DM + f);
        sm.h[w][n][f] = acc;
    }
    __syncthreads();

    // ---- e_src / e_dst ----
    if (tid < 96) {
        int w = tid / 32, r = tid % 32, n = r & 15, which = r >> 4;
        int abase = which ? OFF_ADST : OFF_ASRC;
        float acc = 0.f;
        #pragma unroll
        for (int f = 0; f < DM; ++f) acc += sm.h[w][n][f] * lwf(smW, abase + f);
        if (which) sm.edst[w][n] = acc; else sm.esrc[w][n] = acc;
    }
    __syncthreads();

    // ---- alpha: softmax over sources per (w, dst) ----
    if (tid < 48) {
        int w = tid / 16, d = tid & 15;
        float ed = sm.edst[w][d];
        float e[16];
        float mx = -1e30f;
        #pragma unroll
        for (int s = 0; s < 16; ++s) {
            float x = sm.esrc[w][s] + ed;
            x = x > 0.f ? x : 0.2f * x;   // leaky_relu(0.2)
            e[s] = x;
            mx = fmaxf(mx, x);
        }
        float sum = 0.f;
        #pragma unroll
        for (int s = 0; s < 16; ++s) { e[s] = __expf(e[s] - mx); sum += e[s]; }
        float inv = 1.f / sum;
        #pragma unroll
        for (int s = 0; s < 16; ++s) sm.alpha[w][s][d] = e[s] * inv;
    }
    __syncthreads();

    // ---- gat_out = elu(alpha^T h) -> tmp ----
    for (int idx = tid; idx < NW * NHOST * DM; idx += 256) {
        int w = idx >> 8, r = idx & 255, d = r >> 4, f = r & 15;
        float acc = 0.f;
        #pragma unroll
        for (int s = 0; s < 16; ++s) acc += sm.alpha[w][s][d] * sm.h[w][s][f];
        sm.tmp[w][d][f] = acc > 0.f ? acc : (__expf(acc) - 1.f);  // elu
    }
    __syncthreads();

    // ---- time encode + positional encode ----
    for (int idx = tid; idx < NW * NHOST * DM; idx += 256) {
        int w = idx >> 8, r = idx & 255, n = r >> 4, f = r & 15;
        float acc = lwf(smW, OFF_TEB + f) + lwf(smW, OFF_PE + w * DM + f);
        #pragma unroll
        for (int g = 0; g < DM; ++g)
            acc += sm.tmp[w][n][g] * lwf(smW, OFF_TEW + f * DM + g);
        sm.xe[w][n][f] = acc;
    }
    __syncthreads();

    // ---- 2 post-norm transformer encoder layers ----
    #pragma unroll 1
    for (int l = 0; l < 2; ++l) {
        int qW = OFF_QKVW + l * 768, qb = OFF_QKVB + l * 48;
        for (int idx = tid; idx < NW * NHOST * 48; idx += 256) {
            int w = idx / (NHOST * 48), r = idx % (NHOST * 48), n = r / 48, j = r % 48;
            float acc = lwf(smW, qb + j);
            #pragma unroll
            for (int f = 0; f < DM; ++f) acc += sm.xe[w][n][f] * lwf(smW, qW + j * DM + f);
            sm.qkv[w][n][j] = acc;
        }
        __syncthreads();

        // attention: one thread per (batch, head, q): 96 threads
        if (tid < 96) {
            int b = tid / 6, r = tid % 6, hh = r / 3, qs = r % 3;
            const float inv_sqrt_hd = 0.35355339059327373f;
            float sc[3];
            #pragma unroll
            for (int ks = 0; ks < 3; ++ks) {
                float acc = 0.f;
                #pragma unroll
                for (int d0 = 0; d0 < 8; ++d0)
                    acc += sm.qkv[qs][b][hh * 8 + d0] * sm.qkv[ks][b][16 + hh * 8 + d0];
                sc[ks] = acc * inv_sqrt_hd;
            }
            float mx = fmaxf(sc[0], fmaxf(sc[1], sc[2]));
            float s0 = __expf(sc[0] - mx), s1 = __expf(sc[1] - mx), s2 = __expf(sc[2] - mx);
            float inv = 1.f / (s0 + s1 + s2);
            s0 *= inv; s1 *= inv; s2 *= inv;
            #pragma unroll
            for (int d0 = 0; d0 < 8; ++d0)
                sm.ctx[qs][b][hh * 8 + d0] = s0 * sm.qkv[0][b][32 + hh * 8 + d0]
                                           + s1 * sm.qkv[1][b][32 + hh * 8 + d0]
                                           + s2 * sm.qkv[2][b][32 + hh * 8 + d0];
        }
        __syncthreads();

        // out projection + residual -> tmp
        int oW = OFF_OUTW + l * 256, ob = OFF_OUTB + l * 16;
        for (int idx = tid; idx < NW * NHOST * DM; idx += 256) {
            int w = idx >> 8, r = idx & 255, n = r >> 4, f = r & 15;
            float acc = lwf(smW, ob + f) + sm.xe[w][n][f];
            #pragma unroll
            for (int g = 0; g < DM; ++g) acc += sm.ctx[w][n][g] * lwf(smW, oW + f * DM + g);
            sm.tmp[w][n][f] = acc;
        }
        __syncthreads();

        // LN1 -> xe
        if (tid < 48) {
            int w = tid / 16, n = tid & 15;
            float m = 0.f;
            #pragma unroll
            for (int f = 0; f < DM; ++f) m += sm.tmp[w][n][f];
            m *= (1.f / 16.f);
            float v = 0.f;
            #pragma unroll
            for (int f = 0; f < DM; ++f) { float d0 = sm.tmp[w][n][f] - m; v += d0 * d0; }
            v *= (1.f / 16.f);
            float rr = rsqrtf(v + 1e-5f);
            #pragma unroll
            for (int f = 0; f < DM; ++f)
                sm.xe[w][n][f] = (sm.tmp[w][n][f] - m) * rr * lwf(smW, OFF_LN1G + l * DM + f)
                               + lwf(smW, OFF_LN1B + l * DM + f);
        }
        __syncthreads();

        // FF1 (relu) -> ffh
        int f1W = OFF_FF1W + l * 1024, f1b = OFF_FF1B + l * 64;
        for (int idx = tid; idx < NW * NHOST * FFD; idx += 256) {
            int w = idx / (NHOST * FFD), r = idx % (NHOST * FFD), n = r / FFD, j = r % FFD;
            float acc = lwf(smW, f1b + j);
            #pragma unroll
            for (int f = 0; f < DM; ++f) acc += sm.xe[w][n][f] * lwf(smW, f1W + j * DM + f);
            sm.ffh[w][n][j] = fmaxf(acc, 0.f);
        }
        __syncthreads();

        // FF2 + residual -> tmp
        int f2W = OFF_FF2W + l * 1024, f2b = OFF_FF2B + l * 16;
        for (int idx = tid; idx < NW * NHOST * DM; idx += 256) {
            int w = idx >> 8, r = idx & 255, n = r >> 4, f = r & 15;
            float acc = lwf(smW, f2b + f) + sm.xe[w][n][f];
            #pragma unroll
            for (int j = 0; j < FFD; ++j) acc += sm.ffh[w][n][j] * lwf(smW, f2W + f * FFD + j);
            sm.tmp[w][n][f] = acc;
        }
        __syncthreads();

        // LN2 -> xe
        if (tid < 48) {
            int w = tid / 16, n = tid & 15;
            float m = 0.f;
            #pragma unroll
            for (int f = 0; f < DM; ++f) m += sm.tmp[w][n][f];
            m *= (1.f / 16.f);
            float v = 0.f;
            #pragma unroll
            for (int f = 0; f < DM; ++f) { float d0 = sm.tmp[w][n][f] - m; v += d0 * d0; }
            v *= (1.f / 16.f);
            float rr = rsqrtf(v + 1e-5f);
            #pragma unroll
            for (int f = 0; f < DM; ++f)
                sm.xe[w][n][f] = (sm.tmp[w][n][f] - m) * rr * lwf(smW, OFF_LN2G + l * DM + f)
                               + lwf(smW, OFF_LN2B + l * DM + f);
        }
        __syncthreads();
    }

    // ---- latent (batch-major) -> LDS ----
    for (int idx = tid; idx < LAT; idx += 256) {
        int w = idx >> 8, r = idx & 255, n = r >> 4, f = r & 15;
        sm.latent[n * 48 + w * DM + f] = sm.xe[w][n][f];
    }
    __syncthreads();

    // ---- decoder: block o computes one 768-dot from its own LDS latent ----
    float acc = 0.f;
    if (tid < 192) {
        int e0 = tid * 4;
        acc = sm.latent[e0]     * gld(&wr0, 0)
            + sm.latent[e0 + 1] * gld(&wr1, 0)
            + sm.latent[e0 + 2] * gld(&wr2, 0)
            + sm.latent[e0 + 3] * gld(&wr3, 0);
    }
    #pragma unroll
    for (int m = 1; m < 64; m <<= 1) acc += __shfl_xor(acc, m);
    if ((tid & 63) == 0) sm.part[tid >> 6] = acc;
    __syncthreads();
    if (tid == 0) {
        float s = sm.part[0] + sm.part[1] + sm.part[2] + sm.part[3];
        if (o < 32) {
            gst(out, o, s + gld(an_b, o));              // leaky(1.0) = identity
        } else {
            float z = s + gld(pr_b, o - 32);
            gst(out, o, 1.f / (1.f + __expf(-z)));      // sigmoid
        }
    }
}

__global__ void __launch_bounds__(256) txf_fused(
    const void* t, const void* gat_W, const void* a_src, const void* a_dst,
    const void* te_W, const void* te_b, const void* pe,
    const void* qkv_W, const void* qkv_b, const void* out_W, const void* out_b,
    const void* ln1_g, const void* ln1_b,
    const void* ff1_W, const void* ff1_b, const void* ff2_W, const void* ff2_b,
    const void* ln2_g, const void* ln2_b,
    const void* an_W, const void* an_b, const void* pr_W, const void* pr_b,
    void* out)
{
    __shared__ Smem sm;
    __shared__ __align__(16) unsigned char wbuf[TOTAL_W * 4];  // max of bf16/f32 arenas
    const int tid = threadIdx.x;
    const int o = blockIdx.x;
    unsigned w0 = *(const unsigned*)ln1_g;   // all-ones sniff
    if (w0 == 0x3F803F80u) {
        run_all<bf16, unsigned short>(sm, (unsigned short*)wbuf, tid, o,
            (const bf16*)t, (const bf16*)gat_W, (const bf16*)a_src, (const bf16*)a_dst,
            (const bf16*)te_W, (const bf16*)te_b, (const bf16*)pe,
            (const bf16*)qkv_W, (const bf16*)qkv_b, (const bf16*)out_W, (const bf16*)out_b,
            (const bf16*)ln1_g, (const bf16*)ln1_b,
            (const bf16*)ff1_W, (const bf16*)ff1_b, (const bf16*)ff2_W, (const bf16*)ff2_b,
            (const bf16*)ln2_g, (const bf16*)ln2_b,
            (const bf16*)an_W, (const bf16*)an_b, (const bf16*)pr_W, (const bf16*)pr_b,
            (bf16*)out);
    } else {
        run_all<float, float>(sm, (float*)wbuf, tid, o,
            (const float*)t, (const float*)gat_W, (const float*)a_src, (const float*)a_dst,
            (const float*)te_W, (const float*)te_b, (const float*)pe,
            (const float*)qkv_W, (const float*)qkv_b, (const float*)out_W, (const float*)out_b,
            (const float*)ln1_g, (const float*)ln1_b,
            (const float*)ff1_W, (const float*)ff1_b, (const float*)ff2_W, (const float*)ff2_b,
            (const float*)ln2_g, (const float*)ln2_b,
            (const float*)an_W, (const float*)an_b, (const float*)pr_W, (const float*)pr_b,
            (float*)out);
    }
}

extern "C" void kernel_launch(void* const* d_in, const int* in_sizes, int n_in,
                              void* d_out, int out_size, void* d_ws, size_t ws_size,
                              hipStream_t stream) {
    txf_fused<<<160, 256, 0, stream>>>(
        d_in[0],                                 // t  (d_in[1] = s unused)
        d_in[2], d_in[3], d_in[4],               // gat_W, a_src, a_dst
        d_in[5], d_in[6], d_in[7],               // te_W, te_b, pe
        d_in[8], d_in[9], d_in[10], d_in[11],    // qkv_W, qkv_b, out_W, out_b
        d_in[12], d_in[13],                      // ln1_g, ln1_b
        d_in[14], d_in[15], d_in[16], d_in[17],  // ff1_W, ff1_b, ff2_W, ff2_b
        d_in[18], d_in[19],                      // ln2_g, ln2_b
        d_in[20], d_in[21], d_in[22], d_in[23],  // an_W, an_b, pr_W, pr_b
        d_out);
}

// Round 7
// 124.185 us; speedup vs baseline: 1.0229x; 1.0229x over previous
//
#include <hip/hip_runtime.h>
#include <hip/hip_bf16.h>

// Single fused kernel, grid = 160 blocks x 256 threads.
// Proven structure (R6): dtype sniff via ln1_g, LDS weight arena in input
// dtype, per-block redundant encode, block o -> decoder output o.
// New (R7): vectorized LDS reads (float4 / ushort8) + register-cached rows
// + stage fusion, cutting LDS instruction count ~5x (encode was
// LDS-issue-throughput-bound: ~700K scalar ds_reads ~= 26us).

#define NW 3
#define NHOST 16
#define DM 16
#define FFD 64
#define LAT 768

typedef __hip_bfloat16 bf16;
typedef __attribute__((ext_vector_type(8))) unsigned short ushort8v;

static __device__ __forceinline__ float u2f(unsigned short u) {
    return __uint_as_float(((unsigned)u) << 16);
}

// arena scalar read (arena stored in input dtype)
static __device__ __forceinline__ float lwf(const unsigned short* a, int i) { return u2f(a[i]); }
static __device__ __forceinline__ float lwf(const float* a, int i) { return a[i]; }

// arena vector reads: 8/16 consecutive elems -> fp32 (off multiple of 8)
static __device__ __forceinline__ void wld8(const unsigned short* a, int off, float* o) {
    ushort8v v = *(const ushort8v*)(a + off);
    #pragma unroll
    for (int u = 0; u < 8; ++u) o[u] = u2f(v[u]);
}
static __device__ __forceinline__ void wld8(const float* a, int off, float* o) {
    float4 x = *(const float4*)(a + off);
    float4 y = *(const float4*)(a + off + 4);
    o[0]=x.x; o[1]=x.y; o[2]=x.z; o[3]=x.w; o[4]=y.x; o[5]=y.y; o[6]=y.z; o[7]=y.w;
}
template<typename WT>
static __device__ __forceinline__ void wld16(const WT* a, int off, float* o) {
    wld8(a, off, o); wld8(a, off + 8, o + 8);
}

// fp32 LDS row helpers (16B-aligned)
static __device__ __forceinline__ void ldrow8(const float* p, float* o) {
    float4 x = ((const float4*)p)[0], y = ((const float4*)p)[1];
    o[0]=x.x; o[1]=x.y; o[2]=x.z; o[3]=x.w; o[4]=y.x; o[5]=y.y; o[6]=y.z; o[7]=y.w;
}
static __device__ __forceinline__ void ldrow16(const float* p, float* o) {
    ldrow8(p, o); ldrow8(p + 8, o + 8);
}
static __device__ __forceinline__ void strow16(float* p, const float* o) {
    #pragma unroll
    for (int c = 0; c < 4; ++c) {
        float4 v = { o[c*4+0], o[c*4+1], o[c*4+2], o[c*4+3] };
        ((float4*)p)[c] = v;
    }
}

// global scalar load / store
static __device__ __forceinline__ float gld(const bf16* p, int i) { return __bfloat162float(p[i]); }
static __device__ __forceinline__ float gld(const float* p, int i) { return p[i]; }
static __device__ __forceinline__ void gst(bf16* p, int i, float v) { p[i] = __float2bfloat16(v); }
static __device__ __forceinline__ void gst(float* p, int i, float v) { p[i] = v; }

// ---- LDS weight-arena element offsets (all multiples of 8) ----
enum {
    OFF_T    = 0,     // 144
    OFF_GATW = 144,   // 48
    OFF_ASRC = 192,   // 16
    OFF_ADST = 208,   // 16
    OFF_TEW  = 224,   // 256
    OFF_TEB  = 480,   // 16
    OFF_PE   = 496,   // 48
    OFF_QKVW = 544,   // 1536
    OFF_QKVB = 2080,  // 96
    OFF_OUTW = 2176,  // 512
    OFF_OUTB = 2688,  // 32
    OFF_LN1G = 2720,  // 32
    OFF_LN1B = 2752,  // 32
    OFF_FF1W = 2784,  // 2048
    OFF_FF1B = 4832,  // 128
    OFF_FF2W = 4960,  // 2048
    OFF_FF2B = 7008,  // 32
    OFF_LN2G = 7040,  // 32
    OFF_LN2B = 7072,  // 32
    TOTAL_W  = 7104
};

struct __align__(16) Smem {
    float h[NW][NHOST][DM];       // 3072 B, every member 16B-aligned
    float esrc[NW][NHOST];
    float edst[NW][NHOST];
    float xe[NW][NHOST][DM];
    float qkv[NW][NHOST][48];
    float tmp[NW][NHOST][DM];
    float ffh[NW][NHOST][FFD];
    float latent[LAT];
    float part[4];
};

template<typename T, typename WT>
__device__ void run_all(Smem& sm, WT* smW, int tid, int o,
    const T* t, const T* gat_W, const T* a_src, const T* a_dst,
    const T* te_W, const T* te_b, const T* pe,
    const T* qkv_W, const T* qkv_b, const T* out_W, const T* out_b,
    const T* ln1_g, const T* ln1_b,
    const T* ff1_W, const T* ff1_b, const T* ff2_W, const T* ff2_b,
    const T* ln2_g, const T* ln2_b,
    const T* an_W, const T* an_b, const T* pr_W, const T* pr_b,
    T* out)
{
    // ---- prefetch this block's decoder weight slice (hidden behind encode)
    T wr0{}, wr1{}, wr2{}, wr3{};
    if (tid < 192) {
        const T* Wr = (o < 32) ? (an_W + o * LAT) : (pr_W + (o - 32) * LAT);
        wr0 = Wr[tid * 4];     wr1 = Wr[tid * 4 + 1];
        wr2 = Wr[tid * 4 + 2]; wr3 = Wr[tid * 4 + 3];
    }

    // ---- stage all encoder weights + input into LDS (proven loop) ----
    {
        constexpr int EPC = 16 / (int)sizeof(T);
        constexpr int NCHUNK = TOTAL_W / EPC;
        for (int g = tid; g < NCHUNK; g += 256) {
            int e = g * EPC;
            const T* p; int base;
            if      (e < OFF_GATW) { p = t;      base = OFF_T; }
            else if (e < OFF_ASRC) { p = gat_W;  base = OFF_GATW; }
            else if (e < OFF_ADST) { p = a_src;  base = OFF_ASRC; }
            else if (e < OFF_TEW)  { p = a_dst;  base = OFF_ADST; }
            else if (e < OFF_TEB)  { p = te_W;   base = OFF_TEW; }
            else if (e < OFF_PE)   { p = te_b;   base = OFF_TEB; }
            else if (e < OFF_QKVW) { p = pe;     base = OFF_PE; }
            else if (e < OFF_QKVB) { p = qkv_W;  base = OFF_QKVW; }
            else if (e < OFF_OUTW) { p = qkv_b;  base = OFF_QKVB; }
            else if (e < OFF_OUTB) { p = out_W;  base = OFF_OUTW; }
            else if (e < OFF_LN1G) { p = out_b;  base = OFF_OUTB; }
            else if (e < OFF_LN1B) { p = ln1_g;  base = OFF_LN1G; }
            else if (e < OFF_FF1W) { p = ln1_b;  base = OFF_LN1B; }
            else if (e < OFF_FF1B) { p = ff1_W;  base = OFF_FF1W; }
            else if (e < OFF_FF2W) { p = ff1_b;  base = OFF_FF1B; }
            else if (e < OFF_FF2B) { p = ff2_W;  base = OFF_FF2W; }
            else if (e < OFF_LN2G) { p = ff2_b;  base = OFF_FF2B; }
            else if (e < OFF_LN2B) { p = ln2_g;  base = OFF_LN2G; }
            else                   { p = ln2_b;  base = OFF_LN2B; }
            *(ushort8v*)((unsigned char*)smW + (size_t)e * sizeof(T)) =
                *(const ushort8v*)(p + (e - base));
        }
    }
    __syncthreads();

    // ---- GAT h-rows + attention logits, fused: one thread per (w,n) ----
    if (tid < 48) {
        int w = tid / 16, n = tid & 15;
        float x0 = lwf(smW, OFF_T + (w * NHOST + n) * 3 + 0);
        float x1 = lwf(smW, OFF_T + (w * NHOST + n) * 3 + 1);
        float x2 = lwf(smW, OFF_T + (w * NHOST + n) * 3 + 2);
        float g0[16], g1[16], g2[16];
        wld16(smW, OFF_GATW, g0);
        wld16(smW, OFF_GATW + 16, g1);
        wld16(smW, OFF_GATW + 32, g2);
        float hr[16];
        #pragma unroll
        for (int f = 0; f < 16; ++f) hr[f] = x0 * g0[f] + x1 * g1[f] + x2 * g2[f];
        strow16(sm.h[w][n], hr);
        float as[16], ad[16];
        wld16(smW, OFF_ASRC, as);
        wld16(smW, OFF_ADST, ad);
        float es = 0.f, ed = 0.f;
        #pragma unroll
        for (int f = 0; f < 16; ++f) { es += hr[f] * as[f]; ed += hr[f] * ad[f]; }
        sm.esrc[w][n] = es; sm.edst[w][n] = ed;
    }
    __syncthreads();

    // ---- softmax-over-sources + aggregate + ELU + time/pos encode, fused ----
    if (tid < 48) {
        int w = tid / 16, d = tid & 15;
        float ed = sm.edst[w][d];
        float er[16]; ldrow16(sm.esrc[w], er);
        float e[16], mx = -1e30f;
        #pragma unroll
        for (int s = 0; s < 16; ++s) {
            float x = er[s] + ed;
            x = x > 0.f ? x : 0.2f * x;          // leaky_relu(0.2)
            e[s] = x; mx = fmaxf(mx, x);
        }
        float sum = 0.f;
        #pragma unroll
        for (int s = 0; s < 16; ++s) { e[s] = __expf(e[s] - mx); sum += e[s]; }
        float inv = 1.f / sum;
        float row[16];
        #pragma unroll
        for (int f = 0; f < 16; ++f) row[f] = 0.f;
        #pragma unroll
        for (int s = 0; s < 16; ++s) {
            float a = e[s] * inv;
            float hs[16]; ldrow16(sm.h[w][s], hs);
            #pragma unroll
            for (int f = 0; f < 16; ++f) row[f] += a * hs[f];
        }
        #pragma unroll
        for (int f = 0; f < 16; ++f)
            row[f] = row[f] > 0.f ? row[f] : (__expf(row[f]) - 1.f);   // ELU
        // time encode: xe[f] = te_b[f] + pe[w][f] + sum_g row[g]*te_W[f][g]
        float xr[16];
        #pragma unroll
        for (int f = 0; f < 16; ++f) {
            float wv[16]; wld16(smW, OFF_TEW + f * 16, wv);
            float acc = lwf(smW, OFF_TEB + f) + lwf(smW, OFF_PE + w * 16 + f);
            #pragma unroll
            for (int g = 0; g < 16; ++g) acc += row[g] * wv[g];
            xr[f] = acc;
        }
        strow16(sm.xe[w][d], xr);
    }
    __syncthreads();

    // ---- 2 post-norm transformer encoder layers ----
    #pragma unroll 1
    for (int l = 0; l < 2; ++l) {
        const int qW = OFF_QKVW + l * 768, qb = OFF_QKVB + l * 48;
        const int oW = OFF_OUTW + l * 256, ob = OFF_OUTB + l * 16;
        const int f1W = OFF_FF1W + l * 1024, f1b = OFF_FF1B + l * 64;
        const int f2W = OFF_FF2W + l * 1024, f2b = OFF_FF2B + l * 16;

        // QKV: thread = row r (48) x quarter q (4) -> 12 outputs each
        if (tid < 192) {
            int r = tid >> 2, q = tid & 3;
            int w = r / 16, n = r & 15;
            float x[16]; ldrow16(sm.xe[w][n], x);
            int j0 = q * 12;
            #pragma unroll
            for (int j = j0; j < j0 + 12; ++j) {
                float wv[16]; wld16(smW, qW + j * 16, wv);
                float acc = lwf(smW, qb + j);
                #pragma unroll
                for (int g = 0; g < 16; ++g) acc += x[g] * wv[g];
                sm.qkv[w][n][j] = acc;
            }
        }
        __syncthreads();

        // attention + out-proj + residual + LN1, fused: thread = (b, qs)
        if (tid < 48) {
            int b = tid / 3, qs = tid - 3 * b;
            const float isq = 0.35355339059327373f;
            float ctxr[16];
            #pragma unroll
            for (int hh = 0; hh < 2; ++hh) {
                float qh[8]; ldrow8(&sm.qkv[qs][b][hh * 8], qh);
                float sc[3];
                #pragma unroll
                for (int ks = 0; ks < 3; ++ks) {
                    float kh[8]; ldrow8(&sm.qkv[ks][b][16 + hh * 8], kh);
                    float acc = 0.f;
                    #pragma unroll
                    for (int dd = 0; dd < 8; ++dd) acc += qh[dd] * kh[dd];
                    sc[ks] = acc * isq;
                }
                float mx = fmaxf(sc[0], fmaxf(sc[1], sc[2]));
                float s0 = __expf(sc[0] - mx), s1 = __expf(sc[1] - mx), s2 = __expf(sc[2] - mx);
                float inv = 1.f / (s0 + s1 + s2);
                s0 *= inv; s1 *= inv; s2 *= inv;
                #pragma unroll
                for (int dd = 0; dd < 8; ++dd) ctxr[hh * 8 + dd] = 0.f;
                float vh[8];
                ldrow8(&sm.qkv[0][b][32 + hh * 8], vh);
                #pragma unroll
                for (int dd = 0; dd < 8; ++dd) ctxr[hh * 8 + dd] += s0 * vh[dd];
                ldrow8(&sm.qkv[1][b][32 + hh * 8], vh);
                #pragma unroll
                for (int dd = 0; dd < 8; ++dd) ctxr[hh * 8 + dd] += s1 * vh[dd];
                ldrow8(&sm.qkv[2][b][32 + hh * 8], vh);
                #pragma unroll
                for (int dd = 0; dd < 8; ++dd) ctxr[hh * 8 + dd] += s2 * vh[dd];
            }
            // out-proj + residual
            float xr[16]; ldrow16(sm.xe[qs][b], xr);
            float tr[16];
            #pragma unroll
            for (int f = 0; f < 16; ++f) {
                float wv[16]; wld16(smW, oW + f * 16, wv);
                float acc = lwf(smW, ob + f) + xr[f];
                #pragma unroll
                for (int g = 0; g < 16; ++g) acc += ctxr[g] * wv[g];
                tr[f] = acc;
            }
            // LN1
            float m = 0.f;
            #pragma unroll
            for (int f = 0; f < 16; ++f) m += tr[f];
            m *= (1.f / 16.f);
            float v = 0.f;
            #pragma unroll
            for (int f = 0; f < 16; ++f) { float d0 = tr[f] - m; v += d0 * d0; }
            float rr = rsqrtf(v * (1.f / 16.f) + 1e-5f);
            float g16[16], b16[16];
            wld16(smW, OFF_LN1G + l * 16, g16);
            wld16(smW, OFF_LN1B + l * 16, b16);
            float xo[16];
            #pragma unroll
            for (int f = 0; f < 16; ++f) xo[f] = (tr[f] - m) * rr * g16[f] + b16[f];
            strow16(sm.xe[qs][b], xo);
        }
        __syncthreads();

        // FF1 (relu): thread = row r (48) x quarter q (4) -> 16 outputs each
        if (tid < 192) {
            int r = tid >> 2, q = tid & 3;
            int w = r / 16, n = r & 15;
            float x[16]; ldrow16(sm.xe[w][n], x);
            int j0 = q * 16;
            float fr[16];
            #pragma unroll
            for (int jj = 0; jj < 16; ++jj) {
                int j = j0 + jj;
                float wv[16]; wld16(smW, f1W + j * 16, wv);
                float acc = lwf(smW, f1b + j);
                #pragma unroll
                for (int g = 0; g < 16; ++g) acc += x[g] * wv[g];
                fr[jj] = fmaxf(acc, 0.f);
            }
            strow16(&sm.ffh[w][n][j0], fr);
        }
        __syncthreads();

        // FF2 + residual -> tmp: thread = row r (48) x quarter q (4) -> 4 outputs
        if (tid < 192) {
            int r = tid >> 2, q = tid & 3;
            int w = r / 16, n = r & 15;
            float xr[64];
            #pragma unroll
            for (int c = 0; c < 4; ++c) ldrow16(&sm.ffh[w][n][c * 16], &xr[c * 16]);
            int f0 = q * 4;
            #pragma unroll
            for (int ff = 0; ff < 4; ++ff) {
                int f = f0 + ff;
                float acc = lwf(smW, f2b + f) + sm.xe[w][n][f];
                #pragma unroll
                for (int c = 0; c < 8; ++c) {
                    float wv[8]; wld8(smW, f2W + f * 64 + c * 8, wv);
                    #pragma unroll
                    for (int u = 0; u < 8; ++u) acc += xr[c * 8 + u] * wv[u];
                }
                sm.tmp[w][n][f] = acc;
            }
        }
        __syncthreads();

        // LN2: one thread per (w,n); layer 0 -> xe, layer 1 -> latent (batch-major)
        if (tid < 48) {
            int w = tid / 16, n = tid & 15;
            float tr[16]; ldrow16(sm.tmp[w][n], tr);
            float m = 0.f;
            #pragma unroll
            for (int f = 0; f < 16; ++f) m += tr[f];
            m *= (1.f / 16.f);
            float v = 0.f;
            #pragma unroll
            for (int f = 0; f < 16; ++f) { float d0 = tr[f] - m; v += d0 * d0; }
            float rr = rsqrtf(v * (1.f / 16.f) + 1e-5f);
            float g16[16], b16[16];
            wld16(smW, OFF_LN2G + l * 16, g16);
            wld16(smW, OFF_LN2B + l * 16, b16);
            float xo[16];
            #pragma unroll
            for (int f = 0; f < 16; ++f) xo[f] = (tr[f] - m) * rr * g16[f] + b16[f];
            if (l == 0) strow16(sm.xe[w][n], xo);
            else        strow16(&sm.latent[n * 48 + w * 16], xo);
        }
        __syncthreads();
    }

    // ---- decoder: block o computes one 768-dot from its own LDS latent ----
    float acc = 0.f;
    if (tid < 192) {
        int e0 = tid * 4;
        acc = sm.latent[e0]     * gld(&wr0, 0)
            + sm.latent[e0 + 1] * gld(&wr1, 0)
            + sm.latent[e0 + 2] * gld(&wr2, 0)
            + sm.latent[e0 + 3] * gld(&wr3, 0);
    }
    #pragma unroll
    for (int m = 1; m < 64; m <<= 1) acc += __shfl_xor(acc, m);
    if ((tid & 63) == 0) sm.part[tid >> 6] = acc;
    __syncthreads();
    if (tid == 0) {
        float s = sm.part[0] + sm.part[1] + sm.part[2] + sm.part[3];
        if (o < 32) {
            gst(out, o, s + gld(an_b, o));              // leaky(1.0) = identity
        } else {
            float z = s + gld(pr_b, o - 32);
            gst(out, o, 1.f / (1.f + __expf(-z)));      // sigmoid
        }
    }
}

__global__ void __launch_bounds__(256) txf_fused(
    const void* t, const void* gat_W, const void* a_src, const void* a_dst,
    const void* te_W, const void* te_b, const void* pe,
    const void* qkv_W, const void* qkv_b, const void* out_W, const void* out_b,
    const void* ln1_g, const void* ln1_b,
    const void* ff1_W, const void* ff1_b, const void* ff2_W, const void* ff2_b,
    const void* ln2_g, const void* ln2_b,
    const void* an_W, const void* an_b, const void* pr_W, const void* pr_b,
    void* out)
{
    __shared__ Smem sm;
    __shared__ __align__(16) unsigned char wbuf[TOTAL_W * 4];  // max of bf16/f32 arenas
    const int tid = threadIdx.x;
    const int o = blockIdx.x;
    unsigned w0 = *(const unsigned*)ln1_g;   // all-ones sniff
    if (w0 == 0x3F803F80u) {
        run_all<bf16, unsigned short>(sm, (unsigned short*)wbuf, tid, o,
            (const bf16*)t, (const bf16*)gat_W, (const bf16*)a_src, (const bf16*)a_dst,
            (const bf16*)te_W, (const bf16*)te_b, (const bf16*)pe,
            (const bf16*)qkv_W, (const bf16*)qkv_b, (const bf16*)out_W, (const bf16*)out_b,
            (const bf16*)ln1_g, (const bf16*)ln1_b,
            (const bf16*)ff1_W, (const bf16*)ff1_b, (const bf16*)ff2_W, (const bf16*)ff2_b,
            (const bf16*)ln2_g, (const bf16*)ln2_b,
            (const bf16*)an_W, (const bf16*)an_b, (const bf16*)pr_W, (const bf16*)pr_b,
            (bf16*)out);
    } else {
        run_all<float, float>(sm, (float*)wbuf, tid, o,
            (const float*)t, (const float*)gat_W, (const float*)a_src, (const float*)a_dst,
            (const float*)te_W, (const float*)te_b, (const float*)pe,
            (const float*)qkv_W, (const float*)qkv_b, (const float*)out_W, (const float*)out_b,
            (const float*)ln1_g, (const float*)ln1_b,
            (const float*)ff1_W, (const float*)ff1_b, (const float*)ff2_W, (const float*)ff2_b,
            (const float*)ln2_g, (const float*)ln2_b,
            (const float*)an_W, (const float*)an_b, (const float*)pr_W, (const float*)pr_b,
            (float*)out);
    }
}

extern "C" void kernel_launch(void* const* d_in, const int* in_sizes, int n_in,
                              void* d_out, int out_size, void* d_ws, size_t ws_size,
                              hipStream_t stream) {
    txf_fused<<<160, 256, 0, stream>>>(
        d_in[0],                                 // t  (d_in[1] = s unused)
        d_in[2], d_in[3], d_in[4],               // gat_W, a_src, a_dst
        d_in[5], d_in[6], d_in[7],               // te_W, te_b, pe
        d_in[8], d_in[9], d_in[10], d_in[11],    // qkv_W, qkv_b, out_W, out_b
        d_in[12], d_in[13],                      // ln1_g, ln1_b
        d_in[14], d_in[15], d_in[16], d_in[17],  // ff1_W, ff1_b, ff2_W, ff2_b
        d_in[18], d_in[19],                      // ln2_g, ln2_b
        d_in[20], d_in[21], d_in[22], d_in[23],  // an_W, an_b, pr_W, pr_b
        d_out);
}